// Round 5
// baseline (142.202 us; speedup 1.0000x reference)
//
#include <hip/hip_runtime.h>

#define D    300
#define NF4  75            // 300 floats = 75 float4 per row
#define K    10
#define WPB  4             // waves per block
#define GPB  16            // 16-lane row-groups per block
#define NBLOCKS 2048
#define NGROUPS (NBLOCKS * GPB)   // 32768 = 2^15
#define LOG2_NGROUPS 15

#define P2_BLOCKS  64
#define P2_THREADS 1024
#define P2_CPT     7       // ceil(400000/64/1024)

__device__ __forceinline__ float d4(float4 a, float4 b) {
    return a.x*b.x + a.y*b.y + a.z*b.z + a.w*b.w;
}

#define RED16(x) { x += __shfl_xor(x, 8, 64); x += __shfl_xor(x, 4, 64); \
                   x += __shfl_xor(x, 2, 64); x += __shfl_xor(x, 1, 64); }

// ---------------- Phase 1: cosine for ALL rows -> score[] ----------------
// 16 lanes per row, 4 rows per wave, CONTIGUOUS span per group (sequential
// DRAM pages per stream), depth-2 rotated register pipeline.
__global__ __launch_bounds__(256) void cos_all(
    const float* __restrict__ emb, const float* __restrict__ wvec,
    float* __restrict__ score, int V)
{
    const int tid  = threadIdx.x;
    const int lane = tid & 63;
    const int wid  = tid >> 6;
    const int l16  = lane & 15;
    const int rg   = lane >> 4;
    const bool tl  = (l16 < NF4 - 64);     // 11 tail lanes

    const float4* w4p = (const float4*)wvec;
    float4 w0 = w4p[l16];
    float4 w1 = w4p[l16 + 16];
    float4 w2 = w4p[l16 + 32];
    float4 w3 = w4p[l16 + 48];
    float4 w4t = make_float4(0.f, 0.f, 0.f, 0.f);
    if (tl) w4t = w4p[l16 + 64];

    float qsq = d4(w0,w0)+d4(w1,w1)+d4(w2,w2)+d4(w3,w3)+d4(w4t,w4t);
    RED16(qsq);
    const float qn = sqrtf(qsq);

    // contiguous span for this group: [start, end)
    const int g     = (blockIdx.x * WPB + wid) * 4 + rg;
    const int start = (int)(((long long)g       * V) >> LOG2_NGROUPS);
    const int end   = (int)(((long long)(g + 1) * V) >> LOG2_NGROUPS);

    const float4* pA = (const float4*)emb + (size_t)start * NF4;  // row r
    const float4* pB = pA + NF4;                                  // row r+1

    float4 A0,A1,A2,A3,A4, B0,B1,B2,B3,B4;
    A4 = make_float4(0.f,0.f,0.f,0.f);
    B4 = make_float4(0.f,0.f,0.f,0.f);

#define LOADROW(P, C0,C1,C2,C3,C4) \
    { C0 = (P)[l16]; C1 = (P)[l16+16]; C2 = (P)[l16+32]; C3 = (P)[l16+48]; \
      if (tl) C4 = (P)[l16+64]; }

#define DOTSQ(C0,C1,C2,C3,C4, DOT, SQ)                       \
    float DOT, SQ;                                           \
    {   float _da = d4(C0,w0) + d4(C1,w1);                   \
        float _db = d4(C2,w2) + d4(C3,w3) + d4(C4,w4t);      \
        float _sa = d4(C0,C0) + d4(C1,C1);                   \
        float _sb = d4(C2,C2) + d4(C3,C3) + d4(C4,C4);       \
        DOT = _da + _db; SQ = _sa + _sb; }

#define FINISH(DOT, SQ, ROW)                                 \
    { RED16(DOT); RED16(SQ);                                 \
      float _c = DOT / (sqrtf(SQ + 1e-9f) * qn);             \
      if (l16 == 0) score[ROW] = _c; }

    // prologue: every group has >= 12 rows, so rows start, start+1 exist
    LOADROW(pA, A0,A1,A2,A3,A4);
    LOADROW(pB, B0,B1,B2,B3,B4);

    int r = start;
    while (r + 1 < end) {                  // group-uniform
        {
            DOTSQ(A0,A1,A2,A3,A4, dA, sA);
            if (r + 2 < end) {             // prefetch row r+2
                pA += 2 * NF4;
                LOADROW(pA, A0,A1,A2,A3,A4);
            }
            FINISH(dA, sA, r);
        }
        {
            DOTSQ(B0,B1,B2,B3,B4, dB, sB);
            if (r + 3 < end) {             // prefetch row r+3
                pB += 2 * NF4;
                LOADROW(pB, B0,B1,B2,B3,B4);
            }
            FINISH(dB, sB, r + 1);
        }
        r += 2;
    }
    if (r < end) {                         // odd span: last row sits in A
        DOTSQ(A0,A1,A2,A3,A4, dT, sT);
        FINISH(dT, sT, r);
    }
#undef LOADROW
#undef DOTSQ
#undef FINISH
}

// ---------------- Phase 2a: exact per-block top-10 over score chunks ----------------
__global__ __launch_bounds__(P2_THREADS) void block_topk(
    const float* __restrict__ score, int V,
    float* __restrict__ cand_v, int* __restrict__ cand_i)
{
    __shared__ float rv[16];
    __shared__ int   rp[16];
    __shared__ int   s_bp;

    const int tid  = threadIdx.x;
    const int lane = tid & 63;
    const int wid  = tid >> 6;
    const int per  = (V + gridDim.x - 1) / gridDim.x;
    const int base = blockIdx.x * per;

    float v[P2_CPT];
    #pragma unroll
    for (int t = 0; t < P2_CPT; ++t) {
        int i = tid + t * P2_THREADS;
        v[t] = (i < per && base + i < V) ? score[base + i] : -3e38f;
    }

    for (int p = 0; p < K; ++p) {
        float bestv = -3e38f; int bestpos = 0x7fffffff;
        #pragma unroll
        for (int t = 0; t < P2_CPT; ++t) {
            if (v[t] > bestv) { bestv = v[t]; bestpos = tid + t * P2_THREADS; }
        }
        #pragma unroll
        for (int m = 32; m >= 1; m >>= 1) {
            float ov = __shfl_xor(bestv, m, 64);
            int   op = __shfl_xor(bestpos, m, 64);
            if (ov > bestv || (ov == bestv && op < bestpos)) { bestv = ov; bestpos = op; }
        }
        if (lane == 0) { rv[wid] = bestv; rp[wid] = bestpos; }
        __syncthreads();
        if (tid == 0) {
            float bv = rv[0]; int bp = rp[0];
            for (int i = 1; i < 16; ++i)
                if (rv[i] > bv || (rv[i] == bv && rp[i] < bp)) { bv = rv[i]; bp = rp[i]; }
            cand_v[blockIdx.x*K + p] = bv;
            cand_i[blockIdx.x*K + p] = base + bp;
            s_bp = bp;
        }
        __syncthreads();
        const int wbp = s_bp;
        #pragma unroll
        for (int t = 0; t < P2_CPT; ++t) {
            if (tid + t * P2_THREADS == wbp) v[t] = -3e38f;
        }
        __syncthreads();
    }
}

// ---------------- Phase 2b: final top-10 over 640 candidates ----------------
__global__ __launch_bounds__(P2_THREADS) void final_topk(
    const float* __restrict__ cand_v, const int* __restrict__ cand_i,
    int nc, float* __restrict__ out)
{
    __shared__ float rv[16];
    __shared__ int   rp[16];
    __shared__ int   s_bp;

    const int tid  = threadIdx.x;
    const int lane = tid & 63;
    const int wid  = tid >> 6;

    float v0 = (tid < nc) ? cand_v[tid] : -3e38f;

    for (int p = 0; p < K; ++p) {
        float bestv = v0; int bestpos = tid;
        #pragma unroll
        for (int m = 32; m >= 1; m >>= 1) {
            float ov = __shfl_xor(bestv, m, 64);
            int   op = __shfl_xor(bestpos, m, 64);
            if (ov > bestv || (ov == bestv && op < bestpos)) { bestv = ov; bestpos = op; }
        }
        if (lane == 0) { rv[wid] = bestv; rp[wid] = bestpos; }
        __syncthreads();
        if (tid == 0) {
            float bv = rv[0]; int bp = rp[0];
            for (int i = 1; i < 16; ++i)
                if (rv[i] > bv || (rv[i] == bv && rp[i] < bp)) { bv = rv[i]; bp = rp[i]; }
            out[p]     = bv;
            out[K + p] = (float)cand_i[bp];     // exact < 2^24
            s_bp = bp;
        }
        __syncthreads();
        if (tid == s_bp) v0 = -3e38f;
        __syncthreads();
    }
}

extern "C" void kernel_launch(void* const* d_in, const int* in_sizes, int n_in,
                              void* d_out, int out_size, void* d_ws, size_t ws_size,
                              hipStream_t stream) {
    const float* emb  = (const float*)d_in[0];
    const float* wvec = (const float*)d_in[1];
    const int V = in_sizes[0] / D;

    float* score  = (float*)d_ws;
    float* cand_v = score + V;
    int*   cand_i = (int*)(cand_v + P2_BLOCKS * K);

    cos_all<<<NBLOCKS, 256, 0, stream>>>(emb, wvec, score, V);
    block_topk<<<P2_BLOCKS, P2_THREADS, 0, stream>>>(score, V, cand_v, cand_i);
    final_topk<<<1, P2_THREADS, 0, stream>>>(cand_v, cand_i, P2_BLOCKS * K, (float*)d_out);
}

// Round 6
// 122.145 us; speedup vs baseline: 1.1642x; 1.1642x over previous
//
#include <hip/hip_runtime.h>

#define D    300
#define NF4  75            // 300 floats = 75 float4 per row
#define K    10
#define WPB  4             // waves per block
#define GPB  16            // 16-lane row-groups per block
#define NBLOCKS 2048
#define NGROUPS (NBLOCKS * GPB)   // 32768

#define P2_BLOCKS  64
#define P2_THREADS 1024
#define P2_CPT     7       // ceil(400000/64/1024)

typedef float f32x4 __attribute__((ext_vector_type(4)));

__device__ __forceinline__ f32x4 ntload(const f32x4* p) {
    return __builtin_nontemporal_load(p);
}

__device__ __forceinline__ float d4(f32x4 a, f32x4 b) {
    return a[0]*b[0] + a[1]*b[1] + a[2]*b[2] + a[3]*b[3];
}

#define RED16(x) { x += __shfl_xor(x, 8, 64); x += __shfl_xor(x, 4, 64); \
                   x += __shfl_xor(x, 2, 64); x += __shfl_xor(x, 1, 64); }

// ---------------- Phase 1: cosine for ALL rows -> score[] ----------------
// 16 lanes per row, 4 rows per wave, strided groups, depth-2 rotated pipeline,
// NON-TEMPORAL loads on the embedding stream (single-use data).
__global__ __launch_bounds__(256) void cos_all(
    const float* __restrict__ emb, const float* __restrict__ wvec,
    float* __restrict__ score, int V, int s)
{
    const int tid  = threadIdx.x;
    const int lane = tid & 63;
    const int wid  = tid >> 6;
    const int l16  = lane & 15;
    const int rg   = lane >> 4;
    const bool tl  = (l16 < NF4 - 64);     // 11 tail lanes

    const f32x4* w4p = (const f32x4*)wvec;
    f32x4 w0 = w4p[l16];
    f32x4 w1 = w4p[l16 + 16];
    f32x4 w2 = w4p[l16 + 32];
    f32x4 w3 = w4p[l16 + 48];
    f32x4 w4t = 0.f;
    if (tl) w4t = w4p[l16 + 64];

    float qsq = d4(w0,w0)+d4(w1,w1)+d4(w2,w2)+d4(w3,w3)+d4(w4t,w4t);
    RED16(qsq);
    const float qn = sqrtf(qsq);

    const int g0 = (blockIdx.x * WPB + wid) * 4 + rg;
    const size_t stepF4 = (size_t)s * NF4;

    const f32x4* pA = (const f32x4*)emb + (size_t)g0 * NF4;
    const f32x4* pB = pA + stepF4;

    f32x4 A0,A1,A2,A3,A4, B0,B1,B2,B3,B4;
    A4 = 0.f;
    B4 = 0.f;

#define LOADROW(P, C0,C1,C2,C3,C4) \
    { C0 = ntload((P)+l16);    C1 = ntload((P)+l16+16); \
      C2 = ntload((P)+l16+32); C3 = ntload((P)+l16+48); \
      if (tl) C4 = ntload((P)+l16+64); }

#define DOTSQ(C0,C1,C2,C3,C4, DOT, SQ)                       \
    float DOT, SQ;                                           \
    {   float _da = d4(C0,w0) + d4(C1,w1);                   \
        float _db = d4(C2,w2) + d4(C3,w3) + d4(C4,w4t);      \
        float _sa = d4(C0,C0) + d4(C1,C1);                   \
        float _sb = d4(C2,C2) + d4(C3,C3) + d4(C4,C4);       \
        DOT = _da + _db; SQ = _sa + _sb; }

#define FINISH(DOT, SQ, ROW)                                 \
    { RED16(DOT); RED16(SQ);                                 \
      float _c = DOT / (sqrtf(SQ + 1e-9f) * qn);             \
      if (l16 == 0) score[ROW] = _c; }

    // prologue: rows g0, g0+s always valid (V >= 2s)
    LOADROW(pA, A0,A1,A2,A3,A4);
    LOADROW(pB, B0,B1,B2,B3,B4);

    int rowA = g0;
    int rowB = g0 + s;
    const int nfull = V / s;               // 12 for this shape (even)

    for (int it = 0; it < nfull/2 - 1; ++it) {
        {
            DOTSQ(A0,A1,A2,A3,A4, dA, sA);
            pA += 2*stepF4;
            LOADROW(pA, A0,A1,A2,A3,A4);      // prefetch row rowA+2s
            FINISH(dA, sA, rowA);
            rowA += 2*s;
        }
        {
            DOTSQ(B0,B1,B2,B3,B4, dB, sB);
            pB += 2*stepF4;
            LOADROW(pB, B0,B1,B2,B3,B4);      // prefetch row rowB+2s
            FINISH(dB, sB, rowB);
            rowB += 2*s;
        }
    }

    // epilogue: A = row nfull-2, B = row nfull-1, optional tail row nfull
    {
        DOTSQ(A0,A1,A2,A3,A4, dA, sA);
        const bool hasTail = (rowA + 2*s) < V;   // group-uniform
        if (hasTail) { pA += 2*stepF4; LOADROW(pA, A0,A1,A2,A3,A4); }
        FINISH(dA, sA, rowA);
        {
            DOTSQ(B0,B1,B2,B3,B4, dB, sB);
            FINISH(dB, sB, rowB);
        }
        if (hasTail) {
            DOTSQ(A0,A1,A2,A3,A4, dT, sT);
            FINISH(dT, sT, rowA + 2*s);
        }
    }
#undef LOADROW
#undef DOTSQ
#undef FINISH
}

// ---------------- Phase 2a: exact per-block top-10 over score chunks ----------------
__global__ __launch_bounds__(P2_THREADS) void block_topk(
    const float* __restrict__ score, int V,
    float* __restrict__ cand_v, int* __restrict__ cand_i)
{
    __shared__ float rv[16];
    __shared__ int   rp[16];
    __shared__ int   s_bp;

    const int tid  = threadIdx.x;
    const int lane = tid & 63;
    const int wid  = tid >> 6;
    const int per  = (V + gridDim.x - 1) / gridDim.x;
    const int base = blockIdx.x * per;

    float v[P2_CPT];
    #pragma unroll
    for (int t = 0; t < P2_CPT; ++t) {
        int i = tid + t * P2_THREADS;
        v[t] = (i < per && base + i < V) ? score[base + i] : -3e38f;
    }

    for (int p = 0; p < K; ++p) {
        float bestv = -3e38f; int bestpos = 0x7fffffff;
        #pragma unroll
        for (int t = 0; t < P2_CPT; ++t) {
            if (v[t] > bestv) { bestv = v[t]; bestpos = tid + t * P2_THREADS; }
        }
        #pragma unroll
        for (int m = 32; m >= 1; m >>= 1) {
            float ov = __shfl_xor(bestv, m, 64);
            int   op = __shfl_xor(bestpos, m, 64);
            if (ov > bestv || (ov == bestv && op < bestpos)) { bestv = ov; bestpos = op; }
        }
        if (lane == 0) { rv[wid] = bestv; rp[wid] = bestpos; }
        __syncthreads();
        if (tid == 0) {
            float bv = rv[0]; int bp = rp[0];
            for (int i = 1; i < 16; ++i)
                if (rv[i] > bv || (rv[i] == bv && rp[i] < bp)) { bv = rv[i]; bp = rp[i]; }
            cand_v[blockIdx.x*K + p] = bv;
            cand_i[blockIdx.x*K + p] = base + bp;
            s_bp = bp;
        }
        __syncthreads();
        const int wbp = s_bp;
        #pragma unroll
        for (int t = 0; t < P2_CPT; ++t) {
            if (tid + t * P2_THREADS == wbp) v[t] = -3e38f;
        }
        __syncthreads();
    }
}

// ---------------- Phase 2b: final top-10 over 640 candidates ----------------
__global__ __launch_bounds__(P2_THREADS) void final_topk(
    const float* __restrict__ cand_v, const int* __restrict__ cand_i,
    int nc, float* __restrict__ out)
{
    __shared__ float rv[16];
    __shared__ int   rp[16];
    __shared__ int   s_bp;

    const int tid  = threadIdx.x;
    const int lane = tid & 63;
    const int wid  = tid >> 6;

    float v0 = (tid < nc) ? cand_v[tid] : -3e38f;

    for (int p = 0; p < K; ++p) {
        float bestv = v0; int bestpos = tid;
        #pragma unroll
        for (int m = 32; m >= 1; m >>= 1) {
            float ov = __shfl_xor(bestv, m, 64);
            int   op = __shfl_xor(bestpos, m, 64);
            if (ov > bestv || (ov == bestv && op < bestpos)) { bestv = ov; bestpos = op; }
        }
        if (lane == 0) { rv[wid] = bestv; rp[wid] = bestpos; }
        __syncthreads();
        if (tid == 0) {
            float bv = rv[0]; int bp = rp[0];
            for (int i = 1; i < 16; ++i)
                if (rv[i] > bv || (rv[i] == bv && rp[i] < bp)) { bv = rv[i]; bp = rp[i]; }
            out[p]     = bv;
            out[K + p] = (float)cand_i[bp];     // exact < 2^24
            s_bp = bp;
        }
        __syncthreads();
        if (tid == s_bp) v0 = -3e38f;
        __syncthreads();
    }
}

extern "C" void kernel_launch(void* const* d_in, const int* in_sizes, int n_in,
                              void* d_out, int out_size, void* d_ws, size_t ws_size,
                              hipStream_t stream) {
    const float* emb  = (const float*)d_in[0];
    const float* wvec = (const float*)d_in[1];
    const int V = in_sizes[0] / D;

    float* score  = (float*)d_ws;
    float* cand_v = score + V;
    int*   cand_i = (int*)(cand_v + P2_BLOCKS * K);

    cos_all<<<NBLOCKS, 256, 0, stream>>>(emb, wvec, score, V, NGROUPS);
    block_topk<<<P2_BLOCKS, P2_THREADS, 0, stream>>>(score, V, cand_v, cand_i);
    final_topk<<<1, P2_THREADS, 0, stream>>>(cand_v, cand_i, P2_BLOCKS * K, (float*)d_out);
}